// Round 1
// baseline (195.920 us; speedup 1.0000x reference)
//

#include <hip/hip_runtime.h>
#include <hip/hip_bf16.h>
#include <math.h>

// ArcFace forward: out = S * modified, where modified == logits except at
// (row, label): cos(arccos(t) + MARGIN) = t*cos(m) - sqrt(1-t^2)*sin(m).
// Pure streaming kernel: 100 MB read + 100 MB write -> HBM-bound, ~32us roofline.

#define ARC_S      64.0f
#define COS_M      0.8775825618903728f   // cos(0.5)
#define SIN_M      0.4794255386042030f   // sin(0.5)

__global__ __launch_bounds__(256) void arcface_kernel(
    const float* __restrict__ logits,
    const int*   __restrict__ labels,
    float*       __restrict__ out,
    int C, int C4)
{
    const int row = blockIdx.y;
    const int i4  = blockIdx.x * blockDim.x + threadIdx.x;
    if (i4 >= C4) return;

    const int lbl = labels[row];               // scalar-cached broadcast per row
    const size_t rowOff = (size_t)row * (size_t)C;
    const int base = i4 * 4;

    if (base + 4 <= C) {
        // vector path (covers everything when C % 4 == 0, which holds here)
        const float4* in4  = (const float4*)(logits + rowOff);
        float4*       out4 = (float4*)(out + rowOff);
        float4 v = in4[i4];

        if (lbl >= base && lbl < base + 4) {   // almost always wave-uniform false
            float* pv = (float*)&v;
            const float t  = pv[lbl - base];
            const float s  = sqrtf(fmaxf(0.0f, 1.0f - t * t));
            pv[lbl - base] = t * COS_M - s * SIN_M;
        }

        v.x *= ARC_S; v.y *= ARC_S; v.z *= ARC_S; v.w *= ARC_S;
        out4[i4] = v;
    } else {
        // scalar tail (unused for C=100000 but keeps the kernel general)
        for (int c = base; c < C; ++c) {
            float t = logits[rowOff + c];
            if (c == lbl) {
                const float s = sqrtf(fmaxf(0.0f, 1.0f - t * t));
                t = t * COS_M - s * SIN_M;
            }
            out[rowOff + c] = ARC_S * t;
        }
    }
}

extern "C" void kernel_launch(void* const* d_in, const int* in_sizes, int n_in,
                              void* d_out, int out_size, void* d_ws, size_t ws_size,
                              hipStream_t stream) {
    const float* logits = (const float*)d_in[0];
    const int*   labels = (const int*)d_in[1];
    float*       out    = (float*)d_out;

    const int B = in_sizes[1];                 // 256
    const int C = in_sizes[0] / B;             // 100000
    const int C4 = (C + 3) / 4;                // float4 groups per row

    dim3 block(256, 1, 1);
    dim3 grid((C4 + 255) / 256, B, 1);
    arcface_kernel<<<grid, block, 0, stream>>>(logits, labels, out, C, C4);
}


// Round 3
// 180.629 us; speedup vs baseline: 1.0847x; 1.0847x over previous
//

#include <hip/hip_runtime.h>
#include <hip/hip_bf16.h>
#include <math.h>

// ArcFace forward: out = S * modified, where modified == logits except at
// (row, label): cos(arccos(t) + MARGIN) = t*cos(m) - sqrt(1-t^2)*sin(m).
//
// R1 post-mortem: 1-float4-per-thread version ran at 1.9 TB/s (80us) —
// MLP-limited (1 outstanding load/wave, 100k short-lived waves).
// R2: grid-stride loop, 4 float4 loads in flight per thread, 25 blocks/CU,
// nontemporal stores (output is streaming write-once; keep L3 for the input).
// R3: use native ext_vector_type for nt-store builtin (HIP float4 is a struct
// and __builtin_nontemporal_store rejects it).

#define ARC_S      64.0f
#define COS_M      0.8775825618903728f   // cos(0.5)
#define SIN_M      0.4794255386042030f   // sin(0.5)

typedef float floatx4 __attribute__((ext_vector_type(4)));

__global__ __launch_bounds__(256) void arcface_kernel(
    const float* __restrict__ logits,
    const int*   __restrict__ labels,
    float*       __restrict__ out,
    int C, int C4, int strideV)
{
    const int row = blockIdx.y;
    const int lbl = labels[row];               // L1-cached broadcast per row
    const size_t rowOff = (size_t)row * (size_t)C;
    const floatx4* __restrict__ in4  = (const floatx4*)(logits + rowOff);
    floatx4*       __restrict__ out4 = (floatx4*)(out + rowOff);

    int i4 = blockIdx.x * blockDim.x + threadIdx.x;

    #pragma unroll 4
    for (; i4 < C4; i4 += strideV) {
        floatx4 v = in4[i4];
        const int d = lbl - i4 * 4;
        if (d >= 0 && d < 4) {                 // almost always wave-uniform false
            const float t = v[d];
            const float s = sqrtf(fmaxf(0.0f, 1.0f - t * t));
            v[d] = t * COS_M - s * SIN_M;
        }
        v *= ARC_S;
        __builtin_nontemporal_store(v, &out4[i4]);
    }
}

extern "C" void kernel_launch(void* const* d_in, const int* in_sizes, int n_in,
                              void* d_out, int out_size, void* d_ws, size_t ws_size,
                              hipStream_t stream) {
    const float* logits = (const float*)d_in[0];
    const int*   labels = (const int*)d_in[1];
    float*       out    = (float*)d_out;

    const int B = in_sizes[1];                 // 256
    const int C = in_sizes[0] / B;             // 100000 (divisible by 4)
    const int C4 = C / 4;                      // 25000 float4 groups per row

    const int ITERS = 4;
    const int threads = 256;
    const int gridX = (C4 + threads * ITERS - 1) / (threads * ITERS);  // 25
    const int strideV = gridX * threads;                               // 6400

    dim3 block(threads, 1, 1);
    dim3 grid(gridX, B, 1);                    // 6400 blocks ~= 25 per CU
    arcface_kernel<<<grid, block, 0, stream>>>(logits, labels, out, C, C4, strideV);
}


// Round 4
// 179.695 us; speedup vs baseline: 1.0903x; 1.0052x over previous
//

#include <hip/hip_runtime.h>
#include <hip/hip_bf16.h>
#include <math.h>

// ArcFace forward: out = S * modified, where modified == logits except at
// (row, label): cos(arccos(t) + MARGIN) = t*cos(m) - sqrt(1-t^2)*sin(m).
//
// R3 post-mortem: grid-stride + unroll-4 still latency-bound (2.5 TB/s) —
// per-iteration bounds guard blocks load speculation; ~1 load in flight.
// R4: split into (a) guard-free flat scale-copy: 3125 blocks x 256 thr x 8
// float4 iters EXACTLY covers 256x100000 floats; 8 independent loads issued
// back-to-back per thread, nt-stores. (b) tiny fixup kernel rewrites the 256
// target elements (stream-ordered after the copy).

#define ARC_S      64.0f
#define COS_M      0.8775825618903728f   // cos(0.5)
#define SIN_M      0.4794255386042030f   // sin(0.5)

typedef float floatx4 __attribute__((ext_vector_type(4)));

__global__ __launch_bounds__(256) void scale_copy_kernel(
    const floatx4* __restrict__ in,
    floatx4*       __restrict__ out)
{
    // Each block owns a contiguous chunk of 2048 float4s (32 KB).
    const size_t base = (size_t)blockIdx.x * 2048u + threadIdx.x;

    floatx4 v[8];
    #pragma unroll
    for (int j = 0; j < 8; ++j)        // 8 independent loads, no guards
        v[j] = in[base + j * 256];

    #pragma unroll
    for (int j = 0; j < 8; ++j) {
        floatx4 w = v[j] * ARC_S;
        __builtin_nontemporal_store(w, &out[base + j * 256]);
    }
}

// Handles (1) the 256 target-element fixups, (2) any flat tail not covered
// by full 2048-float4 chunks (empty for 256x100000).
__global__ __launch_bounds__(256) void fixup_kernel(
    const float* __restrict__ logits,
    const int*   __restrict__ labels,
    float*       __restrict__ out,
    int B, int C, size_t tailStart, size_t total)
{
    const int t = threadIdx.x;

    // target fixup: one thread per row
    if (t < B) {
        const int lbl = labels[t];
        if (lbl >= 0 && lbl < C) {
            const size_t idx = (size_t)t * (size_t)C + (size_t)lbl;
            const float x = logits[idx];
            const float s = sqrtf(fmaxf(0.0f, 1.0f - x * x));
            out[idx] = ARC_S * (x * COS_M - s * SIN_M);
        }
    }

    // scalar tail (generic-shape safety; no-op when total % 8192 == 0)
    for (size_t i = tailStart + t; i < total; i += 256)
        out[i] = ARC_S * logits[i];
}

extern "C" void kernel_launch(void* const* d_in, const int* in_sizes, int n_in,
                              void* d_out, int out_size, void* d_ws, size_t ws_size,
                              hipStream_t stream) {
    const float* logits = (const float*)d_in[0];
    const int*   labels = (const int*)d_in[1];
    float*       out    = (float*)d_out;

    const int B = in_sizes[1];                 // 256
    const int C = in_sizes[0] / B;             // 100000
    const size_t total  = (size_t)B * (size_t)C;       // 25.6e6 floats
    const size_t total4 = total / 4;                   // 6.4e6 float4s
    const int    nChunks = (int)(total4 / 2048);       // 3125 full chunks
    const size_t tailStart = (size_t)nChunks * 2048u * 4u;  // == total here

    scale_copy_kernel<<<dim3(nChunks), dim3(256), 0, stream>>>(
        (const floatx4*)logits, (floatx4*)out);
    fixup_kernel<<<dim3(1), dim3(256), 0, stream>>>(
        logits, labels, out, B, C, tailStart, total);
}
